// Round 12
// baseline (136.313 us; speedup 1.0000x reference)
//
#include <hip/hip_runtime.h>
#include <hip/hip_bf16.h>

// Problem constants
#define B_  8
#define L_  1024
#define D_  1024
#define N_  16
#define R_  64
#define NC_ 1000

#define XP_KS   8             // xproj split-K factor
#define XP_TM   64            // xproj rows per block
#define XP_KC   (D_ / XP_KS)  // 128 K per block
#define XP_M    (B_ * L_)     // 8192

#define CH8  8                // scan chunks over L
#define TCH8 (L_ / CH8)       // 128 timesteps per chunk

__device__ __forceinline__ float exp2_fast(float a) {
#if __has_builtin(__builtin_amdgcn_exp2f)
  return __builtin_amdgcn_exp2f(a);
#else
  float r;
  asm("v_exp_f32 %0, %1" : "=v"(r) : "v"(a));
  return r;
#endif
}

// ---------------------------------------------------------------------------
// Kernel 1a: partial xproj. part[ks][m][96] = sum_{k in slice ks} x[m][k]*W[c][k]
// ---------------------------------------------------------------------------
__global__ __launch_bounds__(256) void xproj_kernel(
    const float* __restrict__ x, const float* __restrict__ W,
    float* __restrict__ part) {
  __shared__ float xs[XP_TM][36];
  __shared__ float wt[32][100];
  const int tid = threadIdx.x;
  const int tx = tid & 7;
  const int ty = tid >> 3;
  const int m0 = blockIdx.x * XP_TM;
  const int ks = blockIdx.y;

  float acc[2][12];
#pragma unroll
  for (int r = 0; r < 2; ++r)
#pragma unroll
    for (int j = 0; j < 12; ++j) acc[r][j] = 0.f;

  for (int step = 0; step < XP_KC / 32; ++step) {
    const int kbase = ks * XP_KC + step * 32;
    __syncthreads();
#pragma unroll
    for (int j = 0; j < 2; ++j) {
      const int f4 = tid + j * 256;
      const int row = f4 >> 3, c4 = f4 & 7;
      float4 v = *(const float4*)(x + (size_t)(m0 + row) * D_ + kbase + c4 * 4);
      *(float4*)(&xs[row][c4 * 4]) = v;
    }
#pragma unroll
    for (int j = 0; j < 3; ++j) {
      const int idx = tid + j * 256;
      const int wr = idx >> 3, c4 = idx & 7;
      float4 v = *(const float4*)(W + (size_t)wr * D_ + kbase + c4 * 4);
      wt[c4 * 4 + 0][wr] = v.x;
      wt[c4 * 4 + 1][wr] = v.y;
      wt[c4 * 4 + 2][wr] = v.z;
      wt[c4 * 4 + 3][wr] = v.w;
    }
    __syncthreads();
#pragma unroll 4
    for (int kk = 0; kk < 32; ++kk) {
      const float a0 = xs[ty * 2 + 0][kk];
      const float a1 = xs[ty * 2 + 1][kk];
      const float4 b0 = *(const float4*)(&wt[kk][tx * 12 + 0]);
      const float4 b1 = *(const float4*)(&wt[kk][tx * 12 + 4]);
      const float4 b2 = *(const float4*)(&wt[kk][tx * 12 + 8]);
      acc[0][0] = fmaf(a0, b0.x, acc[0][0]);
      acc[0][1] = fmaf(a0, b0.y, acc[0][1]);
      acc[0][2] = fmaf(a0, b0.z, acc[0][2]);
      acc[0][3] = fmaf(a0, b0.w, acc[0][3]);
      acc[0][4] = fmaf(a0, b1.x, acc[0][4]);
      acc[0][5] = fmaf(a0, b1.y, acc[0][5]);
      acc[0][6] = fmaf(a0, b1.z, acc[0][6]);
      acc[0][7] = fmaf(a0, b1.w, acc[0][7]);
      acc[0][8] = fmaf(a0, b2.x, acc[0][8]);
      acc[0][9] = fmaf(a0, b2.y, acc[0][9]);
      acc[0][10] = fmaf(a0, b2.z, acc[0][10]);
      acc[0][11] = fmaf(a0, b2.w, acc[0][11]);
      acc[1][0] = fmaf(a1, b0.x, acc[1][0]);
      acc[1][1] = fmaf(a1, b0.y, acc[1][1]);
      acc[1][2] = fmaf(a1, b0.z, acc[1][2]);
      acc[1][3] = fmaf(a1, b0.w, acc[1][3]);
      acc[1][4] = fmaf(a1, b1.x, acc[1][4]);
      acc[1][5] = fmaf(a1, b1.y, acc[1][5]);
      acc[1][6] = fmaf(a1, b1.z, acc[1][6]);
      acc[1][7] = fmaf(a1, b1.w, acc[1][7]);
      acc[1][8] = fmaf(a1, b2.x, acc[1][8]);
      acc[1][9] = fmaf(a1, b2.y, acc[1][9]);
      acc[1][10] = fmaf(a1, b2.z, acc[1][10]);
      acc[1][11] = fmaf(a1, b2.w, acc[1][11]);
    }
  }
#pragma unroll
  for (int r = 0; r < 2; ++r) {
    float* p = part + ((size_t)ks * XP_M + m0 + ty * 2 + r) * 96 + tx * 12;
    *(float4*)(p + 0) = make_float4(acc[r][0], acc[r][1], acc[r][2], acc[r][3]);
    *(float4*)(p + 4) = make_float4(acc[r][4], acc[r][5], acc[r][6], acc[r][7]);
    *(float4*)(p + 8) = make_float4(acc[r][8], acc[r][9], acc[r][10], acc[r][11]);
  }
}

// ---------------------------------------------------------------------------
// Kernel 1b: reduce 8 K-slice partials -> xdb[m][96].
// ---------------------------------------------------------------------------
__global__ __launch_bounds__(256) void xreduce_kernel(
    const float* __restrict__ part, float* __restrict__ xdb) {
  const size_t gidx = (size_t)blockIdx.x * 256 + threadIdx.x;
  const float4* p4 = (const float4*)part;
  const size_t stride = (size_t)XP_M * 96 / 4;
  float4 s = p4[gidx];
#pragma unroll
  for (int ks = 1; ks < XP_KS; ++ks) {
    const float4 v = p4[(size_t)ks * stride + gidx];
    s.x += v.x; s.y += v.y; s.z += v.z; s.w += v.w;
  }
  ((float4*)xdb)[gidx] = s;
}

// ---------------------------------------------------------------------------
// Kernel 2: dt GEMM, both operands via LDS (round-8 version, works well).
// ---------------------------------------------------------------------------
__global__ __launch_bounds__(256) void dt_kernel(
    const float* __restrict__ xdb, const float* __restrict__ W_dt,
    const float* __restrict__ b_dt, float* __restrict__ dtb) {
  __shared__ float xst[64][68];
  __shared__ float wt[64][68];
  const int tid = threadIdx.x;
  const int tx = tid & 15;   // d-quad
  const int ty = tid >> 4;   // m-quad
  const int m0 = blockIdx.x * 64;
  const int d0 = blockIdx.y * 64;

  {
    const int qc = tid & 15, rr = tid >> 4;
#pragma unroll
    for (int j = 0; j < 4; ++j) {
      const int row = rr + j * 16;
      const float4 a = *(const float4*)(xdb + (size_t)(m0 + row) * 96 + qc * 4);
      xst[qc * 4 + 0][row] = a.x;
      xst[qc * 4 + 1][row] = a.y;
      xst[qc * 4 + 2][row] = a.z;
      xst[qc * 4 + 3][row] = a.w;
      const float4 w = *(const float4*)(W_dt + (size_t)(d0 + row) * R_ + qc * 4);
      wt[qc * 4 + 0][row] = w.x;
      wt[qc * 4 + 1][row] = w.y;
      wt[qc * 4 + 2][row] = w.z;
      wt[qc * 4 + 3][row] = w.w;
    }
  }
  __syncthreads();

  float acc[4][4];
#pragma unroll
  for (int i = 0; i < 4; ++i)
#pragma unroll
    for (int j = 0; j < 4; ++j) acc[i][j] = 0.f;

#pragma unroll
  for (int k = 0; k < 64; ++k) {
    const float4 bq = *(const float4*)(&wt[k][tx * 4]);
    const float4 aq = *(const float4*)(&xst[k][ty * 4]);
#pragma unroll
    for (int mi = 0; mi < 4; ++mi) {
      const float a = (mi == 0) ? aq.x : (mi == 1) ? aq.y : (mi == 2) ? aq.z : aq.w;
      acc[mi][0] = fmaf(a, bq.x, acc[mi][0]);
      acc[mi][1] = fmaf(a, bq.y, acc[mi][1]);
      acc[mi][2] = fmaf(a, bq.z, acc[mi][2]);
      acc[mi][3] = fmaf(a, bq.w, acc[mi][3]);
    }
  }

  const float4 bd = *(const float4*)(b_dt + d0 + tx * 4);
#pragma unroll
  for (int mi = 0; mi < 4; ++mi) {
    float4 o;
    float s;
    s = acc[mi][0] + bd.x;
    o.x = fmaxf(s, 0.f) + __logf(1.0f + __expf(-fabsf(s)));
    s = acc[mi][1] + bd.y;
    o.y = fmaxf(s, 0.f) + __logf(1.0f + __expf(-fabsf(s)));
    s = acc[mi][2] + bd.z;
    o.z = fmaxf(s, 0.f) + __logf(1.0f + __expf(-fabsf(s)));
    s = acc[mi][3] + bd.w;
    o.w = fmaxf(s, 0.f) + __logf(1.0f + __expf(-fabsf(s)));
    *(float4*)(dtb + (size_t)(m0 + ty * 4 + mi) * D_ + d0 + tx * 4) = o;
  }
}

// ---------------------------------------------------------------------------
// Kernel 3: BARRIER-FREE streaming scan.
// R8/R9/R11 post-mortem: all LDS-staged variants plateau at 41-49 us with
// ~40% stall — the per-tile __syncthreads pairs + staged-load latency are
// structural. Here x/dt skip LDS entirely: lane map (dl=tid&15, n=tid>>4),
// thread owns d pair (d0+2dl, +1) -> a wave's x/dt loads are 16 distinct
// b64 = one 128-B contiguous region, L1-broadcast across the block's 4
// waves. Only B/C (stride-96 over t) go to LDS: the WHOLE chunk (128 x 34
// = 17.4 KB) staged once, ONE barrier per kernel, then b64 broadcast reads.
// Inner loop: 2 global b64 + 1 LDS b64 + ~16 VALU + 2 exp (trans pipe,
// co-issues), zero barriers. VGPR ~50, 8 blocks/CU -> 32 waves/CU stream.
// ---------------------------------------------------------------------------
__global__ __launch_bounds__(256) void scan_kernel(
    const float* __restrict__ x, const float* __restrict__ xdb,
    const float* __restrict__ dtb, const float* __restrict__ A_log,
    float* __restrict__ summ, float* __restrict__ sumx) {
  __shared__ float bcs[TCH8][34];  // B/C interleaved: B[n]->[2n], C[n]->[2n+1]
  const int tid = threadIdx.x;
  const int dl = tid & 15;
  const int n = tid >> 4;          // 0..15
  const int b = blockIdx.x >> 5;   // grid.x = B*32
  const int dtile = blockIdx.x & 31;
  const int c = blockIdx.y;        // 0..7
  const int d0 = dtile * 32;
  const int da = d0 + 2 * dl;
  const int t0 = c * TCH8;

  // stage B/C for the whole chunk: 128 rows x 8 col-quads = 1024 float4
#pragma unroll
  for (int j = 0; j < 4; ++j) {
    const int f4 = tid + j * 256;
    const int row = f4 >> 3;
    const int bc4 = (f4 & 7) * 4;
    const float4 v =
        *(const float4*)(xdb + ((size_t)b * L_ + t0 + row) * 96 + 64 + bc4);
    const int bpos = ((bc4 * 2) & 31) + (bc4 >> 4);
    bcs[row][bpos + 0] = v.x;
    bcs[row][bpos + 2] = v.y;
    bcs[row][bpos + 4] = v.z;
    bcs[row][bpos + 6] = v.w;
  }
  const float LOG2E = 1.44269504089f;
  const float Av0 = -__expf(A_log[(size_t)da * N_ + n]) * LOG2E;
  const float Av1 = -__expf(A_log[(size_t)(da + 1) * N_ + n]) * LOG2E;
  __syncthreads();  // the only block-wide barrier

  const float* xp = x + ((size_t)b * L_ + t0) * D_ + da;
  const float* dp = dtb + ((size_t)b * L_ + t0) * D_ + da;

  float cumP0 = 1.f, loc0 = 0.f, S10 = 0.f, S20 = 0.f, xs0 = 0.f;
  float cumP1 = 1.f, loc1 = 0.f, S11 = 0.f, S21 = 0.f, xs1 = 0.f;

#pragma unroll 4
  for (int t = 0; t < TCH8; ++t) {
    const float2 xv = *(const float2*)(xp + (size_t)t * D_);
    const float2 dv = *(const float2*)(dp + (size_t)t * D_);
    const float2 bc = *(const float2*)(&bcs[t][2 * n]);  // (B[n], C[n])
    const float e0 = exp2_fast(dv.x * Av0);
    const float e1 = exp2_fast(dv.y * Av1);
    cumP0 *= e0;
    loc0 = fmaf(e0, loc0, (dv.x * xv.x) * bc.x);
    S10 = fmaf(cumP0, bc.y, S10);
    S20 = fmaf(loc0, bc.y, S20);
    xs0 += xv.x;
    cumP1 *= e1;
    loc1 = fmaf(e1, loc1, (dv.y * xv.y) * bc.x);
    S11 = fmaf(cumP1, bc.y, S11);
    S21 = fmaf(loc1, bc.y, S21);
    xs1 += xv.y;
  }

  const size_t si = (((size_t)c * B_ + b) * D_ + da) * N_ + n;
  ((float4*)summ)[si] = make_float4(cumP0, S10, S20, loc0);
  ((float4*)summ)[si + N_] = make_float4(cumP1, S11, S21, loc1);
  if (n == 0) {
    *(float2*)(&sumx[((size_t)c * B_ + b) * D_ + da]) = make_float2(xs0, xs1);
  }
}

// ---------------------------------------------------------------------------
// Kernel 3b: exact sequential chunk combine + n-reduce -> pooled.
// ---------------------------------------------------------------------------
__global__ __launch_bounds__(256) void combine_kernel(
    const float* __restrict__ summ, const float* __restrict__ sumx,
    const float* __restrict__ D_param, float* __restrict__ pooled) {
  const int gid = blockIdx.x * 256 + threadIdx.x;  // 0..131071
  const int n = gid & 15;
  const int d = (gid >> 4) & (D_ - 1);
  const int b = gid >> 14;  // 0..7
  float hin = 0.f, acc = 0.f;
  const float4* s4 = (const float4*)summ;
#pragma unroll
  for (int c = 0; c < CH8; ++c) {
    const float4 f = s4[(((size_t)c * B_ + b) * D_ + d) * N_ + n];
    acc = fmaf(hin, f.y, acc) + f.z;
    hin = fmaf(f.x, hin, f.w);
  }
  acc += __shfl_xor(acc, 1);
  acc += __shfl_xor(acc, 2);
  acc += __shfl_xor(acc, 4);
  acc += __shfl_xor(acc, 8);
  if (n == 0) {
    float xst = 0.f;
#pragma unroll
    for (int c = 0; c < CH8; ++c)
      xst += sumx[((size_t)c * B_ + b) * D_ + d];
    pooled[(size_t)b * D_ + d] =
        (acc + D_param[d] * xst) * (1.0f / (float)L_);
  }
}

// ---------------------------------------------------------------------------
// Kernel 4: logits. One wave per class; all 8 batches from LDS-staged pooled.
// ---------------------------------------------------------------------------
__global__ __launch_bounds__(256) void cls_kernel(
    const float* __restrict__ pooled, const float* __restrict__ W_cls,
    const float* __restrict__ b_cls, float* __restrict__ out) {
  __shared__ float pool[B_ * D_];  // 32 KB
  const int tid = threadIdx.x;
  const int c = blockIdx.x * 4 + (tid >> 6);
  const int lane = tid & 63;

#pragma unroll
  for (int j = 0; j < 8; ++j) {
    const int f4 = tid + j * 256;
    ((float4*)pool)[f4] = ((const float4*)pooled)[f4];
  }
  __syncthreads();

  float accb[B_];
#pragma unroll
  for (int b = 0; b < B_; ++b) accb[b] = 0.f;

#pragma unroll
  for (int i = 0; i < 4; ++i) {
    const float4 wv =
        *(const float4*)(W_cls + (size_t)c * D_ + i * 256 + lane * 4);
#pragma unroll
    for (int b = 0; b < B_; ++b) {
      const float4 p = *(const float4*)(&pool[b * D_ + i * 256 + lane * 4]);
      accb[b] = fmaf(wv.x, p.x,
                fmaf(wv.y, p.y, fmaf(wv.z, p.z, fmaf(wv.w, p.w, accb[b]))));
    }
  }
#pragma unroll
  for (int off = 1; off < 64; off <<= 1) {
#pragma unroll
    for (int b = 0; b < B_; ++b) accb[b] += __shfl_xor(accb[b], off);
  }
  if (lane < B_) out[(size_t)lane * NC_ + c] = accb[lane] + b_cls[c];
}

// ---------------------------------------------------------------------------
extern "C" void kernel_launch(void* const* d_in, const int* in_sizes, int n_in,
                              void* d_out, int out_size, void* d_ws,
                              size_t ws_size, hipStream_t stream) {
  const float* x = (const float*)d_in[0];
  const float* A_log = (const float*)d_in[1];
  const float* D_param = (const float*)d_in[2];
  const float* W_xproj = (const float*)d_in[3];
  const float* W_dt = (const float*)d_in[4];
  const float* b_dt = (const float*)d_in[5];
  const float* W_cls = (const float*)d_in[6];
  const float* b_cls = (const float*)d_in[7];
  float* out = (float*)d_out;

  // ws layout, flat, no aliasing (~79 MB of ~268 MB available):
  float* ws_f = (float*)d_ws;
  float* xdb = ws_f;                               // 786,432 f
  float* part = xdb + (size_t)XP_M * 96;           // 6,291,456 f
  float* dtb = part + (size_t)XP_KS * XP_M * 96;   // 8,388,608 f
  float* summ = dtb + (size_t)XP_M * D_;           // 4,194,304 f
  float* sumx = summ + (size_t)CH8 * B_ * D_ * N_ * 4;  // 65,536 f
  float* pooled = sumx + (size_t)CH8 * B_ * D_;    // 8,192 f

  xproj_kernel<<<dim3(XP_M / XP_TM, XP_KS), dim3(256), 0, stream>>>(
      x, W_xproj, part);
  xreduce_kernel<<<dim3(XP_M * 96 / 4 / 256), dim3(256), 0, stream>>>(part,
                                                                      xdb);
  dt_kernel<<<dim3(XP_M / 64, D_ / 64), dim3(256), 0, stream>>>(xdb, W_dt,
                                                                b_dt, dtb);
  scan_kernel<<<dim3(B_ * 32, CH8), dim3(256), 0, stream>>>(x, xdb, dtb,
                                                            A_log, summ, sumx);
  combine_kernel<<<dim3(B_ * D_ * N_ / 256), dim3(256), 0, stream>>>(
      summ, sumx, D_param, pooled);
  cls_kernel<<<dim3(NC_ / 4), dim3(256), 0, stream>>>(pooled, W_cls, b_cls,
                                                      out);
}

// Round 13
// 102.925 us; speedup vs baseline: 1.3244x; 1.3244x over previous
//
#include <hip/hip_runtime.h>
#include <hip/hip_bf16.h>

// Problem constants
#define B_  8
#define L_  1024
#define D_  1024
#define N_  16
#define R_  64
#define NC_ 1000

#define XP_KS   8             // xproj split-K factor
#define XP_TM   64            // xproj rows per block
#define XP_KC   (D_ / XP_KS)  // 128 K per block
#define XP_M    (B_ * L_)     // 8192

#define CH8  8                // scan chunks over L
#define TCH8 (L_ / CH8)       // 128 timesteps per chunk
#define TB   32               // LDS staging batch (timesteps)

__device__ __forceinline__ float exp2_fast(float a) {
#if __has_builtin(__builtin_amdgcn_exp2f)
  return __builtin_amdgcn_exp2f(a);
#else
  float r;
  asm("v_exp_f32 %0, %1" : "=v"(r) : "v"(a));
  return r;
#endif
}

// ---------------------------------------------------------------------------
// Kernel 1a: partial xproj. part[ks][m][96] = sum_{k in slice ks} x[m][k]*W[c][k]
// ---------------------------------------------------------------------------
__global__ __launch_bounds__(256) void xproj_kernel(
    const float* __restrict__ x, const float* __restrict__ W,
    float* __restrict__ part) {
  __shared__ float xs[XP_TM][36];
  __shared__ float wt[32][100];
  const int tid = threadIdx.x;
  const int tx = tid & 7;
  const int ty = tid >> 3;
  const int m0 = blockIdx.x * XP_TM;
  const int ks = blockIdx.y;

  float acc[2][12];
#pragma unroll
  for (int r = 0; r < 2; ++r)
#pragma unroll
    for (int j = 0; j < 12; ++j) acc[r][j] = 0.f;

  for (int step = 0; step < XP_KC / 32; ++step) {
    const int kbase = ks * XP_KC + step * 32;
    __syncthreads();
#pragma unroll
    for (int j = 0; j < 2; ++j) {
      const int f4 = tid + j * 256;
      const int row = f4 >> 3, c4 = f4 & 7;
      float4 v = *(const float4*)(x + (size_t)(m0 + row) * D_ + kbase + c4 * 4);
      *(float4*)(&xs[row][c4 * 4]) = v;
    }
#pragma unroll
    for (int j = 0; j < 3; ++j) {
      const int idx = tid + j * 256;
      const int wr = idx >> 3, c4 = idx & 7;
      float4 v = *(const float4*)(W + (size_t)wr * D_ + kbase + c4 * 4);
      wt[c4 * 4 + 0][wr] = v.x;
      wt[c4 * 4 + 1][wr] = v.y;
      wt[c4 * 4 + 2][wr] = v.z;
      wt[c4 * 4 + 3][wr] = v.w;
    }
    __syncthreads();
#pragma unroll 4
    for (int kk = 0; kk < 32; ++kk) {
      const float a0 = xs[ty * 2 + 0][kk];
      const float a1 = xs[ty * 2 + 1][kk];
      const float4 b0 = *(const float4*)(&wt[kk][tx * 12 + 0]);
      const float4 b1 = *(const float4*)(&wt[kk][tx * 12 + 4]);
      const float4 b2 = *(const float4*)(&wt[kk][tx * 12 + 8]);
      acc[0][0] = fmaf(a0, b0.x, acc[0][0]);
      acc[0][1] = fmaf(a0, b0.y, acc[0][1]);
      acc[0][2] = fmaf(a0, b0.z, acc[0][2]);
      acc[0][3] = fmaf(a0, b0.w, acc[0][3]);
      acc[0][4] = fmaf(a0, b1.x, acc[0][4]);
      acc[0][5] = fmaf(a0, b1.y, acc[0][5]);
      acc[0][6] = fmaf(a0, b1.z, acc[0][6]);
      acc[0][7] = fmaf(a0, b1.w, acc[0][7]);
      acc[0][8] = fmaf(a0, b2.x, acc[0][8]);
      acc[0][9] = fmaf(a0, b2.y, acc[0][9]);
      acc[0][10] = fmaf(a0, b2.z, acc[0][10]);
      acc[0][11] = fmaf(a0, b2.w, acc[0][11]);
      acc[1][0] = fmaf(a1, b0.x, acc[1][0]);
      acc[1][1] = fmaf(a1, b0.y, acc[1][1]);
      acc[1][2] = fmaf(a1, b0.z, acc[1][2]);
      acc[1][3] = fmaf(a1, b0.w, acc[1][3]);
      acc[1][4] = fmaf(a1, b1.x, acc[1][4]);
      acc[1][5] = fmaf(a1, b1.y, acc[1][5]);
      acc[1][6] = fmaf(a1, b1.z, acc[1][6]);
      acc[1][7] = fmaf(a1, b1.w, acc[1][7]);
      acc[1][8] = fmaf(a1, b2.x, acc[1][8]);
      acc[1][9] = fmaf(a1, b2.y, acc[1][9]);
      acc[1][10] = fmaf(a1, b2.z, acc[1][10]);
      acc[1][11] = fmaf(a1, b2.w, acc[1][11]);
    }
  }
#pragma unroll
  for (int r = 0; r < 2; ++r) {
    float* p = part + ((size_t)ks * XP_M + m0 + ty * 2 + r) * 96 + tx * 12;
    *(float4*)(p + 0) = make_float4(acc[r][0], acc[r][1], acc[r][2], acc[r][3]);
    *(float4*)(p + 4) = make_float4(acc[r][4], acc[r][5], acc[r][6], acc[r][7]);
    *(float4*)(p + 8) = make_float4(acc[r][8], acc[r][9], acc[r][10], acc[r][11]);
  }
}

// ---------------------------------------------------------------------------
// Kernel 1b: reduce 8 K-slice partials -> xdb[m][96].
// ---------------------------------------------------------------------------
__global__ __launch_bounds__(256) void xreduce_kernel(
    const float* __restrict__ part, float* __restrict__ xdb) {
  const size_t gidx = (size_t)blockIdx.x * 256 + threadIdx.x;
  const float4* p4 = (const float4*)part;
  const size_t stride = (size_t)XP_M * 96 / 4;
  float4 s = p4[gidx];
#pragma unroll
  for (int ks = 1; ks < XP_KS; ++ks) {
    const float4 v = p4[(size_t)ks * stride + gidx];
    s.x += v.x; s.y += v.y; s.z += v.z; s.w += v.w;
  }
  ((float4*)xdb)[gidx] = s;
}

// ---------------------------------------------------------------------------
// Kernel 2: dt GEMM, both operands via LDS (round-8 version, works well).
// ---------------------------------------------------------------------------
__global__ __launch_bounds__(256) void dt_kernel(
    const float* __restrict__ xdb, const float* __restrict__ W_dt,
    const float* __restrict__ b_dt, float* __restrict__ dtb) {
  __shared__ float xst[64][68];
  __shared__ float wt[64][68];
  const int tid = threadIdx.x;
  const int tx = tid & 15;   // d-quad
  const int ty = tid >> 4;   // m-quad
  const int m0 = blockIdx.x * 64;
  const int d0 = blockIdx.y * 64;

  {
    const int qc = tid & 15, rr = tid >> 4;
#pragma unroll
    for (int j = 0; j < 4; ++j) {
      const int row = rr + j * 16;
      const float4 a = *(const float4*)(xdb + (size_t)(m0 + row) * 96 + qc * 4);
      xst[qc * 4 + 0][row] = a.x;
      xst[qc * 4 + 1][row] = a.y;
      xst[qc * 4 + 2][row] = a.z;
      xst[qc * 4 + 3][row] = a.w;
      const float4 w = *(const float4*)(W_dt + (size_t)(d0 + row) * R_ + qc * 4);
      wt[qc * 4 + 0][row] = w.x;
      wt[qc * 4 + 1][row] = w.y;
      wt[qc * 4 + 2][row] = w.z;
      wt[qc * 4 + 3][row] = w.w;
    }
  }
  __syncthreads();

  float acc[4][4];
#pragma unroll
  for (int i = 0; i < 4; ++i)
#pragma unroll
    for (int j = 0; j < 4; ++j) acc[i][j] = 0.f;

#pragma unroll
  for (int k = 0; k < 64; ++k) {
    const float4 bq = *(const float4*)(&wt[k][tx * 4]);
    const float4 aq = *(const float4*)(&xst[k][ty * 4]);
#pragma unroll
    for (int mi = 0; mi < 4; ++mi) {
      const float a = (mi == 0) ? aq.x : (mi == 1) ? aq.y : (mi == 2) ? aq.z : aq.w;
      acc[mi][0] = fmaf(a, bq.x, acc[mi][0]);
      acc[mi][1] = fmaf(a, bq.y, acc[mi][1]);
      acc[mi][2] = fmaf(a, bq.z, acc[mi][2]);
      acc[mi][3] = fmaf(a, bq.w, acc[mi][3]);
    }
  }

  const float4 bd = *(const float4*)(b_dt + d0 + tx * 4);
#pragma unroll
  for (int mi = 0; mi < 4; ++mi) {
    float4 o;
    float s;
    s = acc[mi][0] + bd.x;
    o.x = fmaxf(s, 0.f) + __logf(1.0f + __expf(-fabsf(s)));
    s = acc[mi][1] + bd.y;
    o.y = fmaxf(s, 0.f) + __logf(1.0f + __expf(-fabsf(s)));
    s = acc[mi][2] + bd.z;
    o.z = fmaxf(s, 0.f) + __logf(1.0f + __expf(-fabsf(s)));
    s = acc[mi][3] + bd.w;
    o.w = fmaxf(s, 0.f) + __logf(1.0f + __expf(-fabsf(s)));
    *(float4*)(dtb + (size_t)(m0 + ty * 4 + mi) * D_ + d0 + tx * 4) = o;
  }
}

// ---------------------------------------------------------------------------
// Kernel 3: R8 LDS-staged scan + register double-buffer (T14 async-split).
// R12 lesson: per-lane global streaming regresses (VMEM-issue/latency-bound);
// LDS staging of x/dt is essential. R8's cost structure: ~24 us VALU issue
// (exp is trans-pipe, co-issues) + exposed staging latency with TWO barriers
// per 32-t tile. Here: prefetch tile k+1 into registers right after the
// barrier, compute tile k from buf[cur], write regs to buf[cur^1] at next
// iteration top -> ONE barrier per tile, global latency hidden under ~900
// cyc of compute. Write-target buffer's last readers provably passed the
// previous barrier (program order), so one barrier suffices.
// Block 256 = 16 dl x 16 n, thread owns d pair. Grid (B*32, CH8) = 2048.
// LDS 2 x 12.5 KB = 25 KB -> 6 blocks/CU.
// ---------------------------------------------------------------------------
__global__ __launch_bounds__(256) void scan_kernel(
    const float* __restrict__ x, const float* __restrict__ xdb,
    const float* __restrict__ dtb, const float* __restrict__ A_log,
    float* __restrict__ summ, float* __restrict__ sumx) {
  __shared__ float dts[2][TB][32];
  __shared__ float dtx[2][TB][32];
  __shared__ float bcs[2][TB][34];
  const int tid = threadIdx.x;
  const int n = tid & 15;
  const int dl = tid >> 4;          // 0..15
  const int b = blockIdx.x >> 5;    // 0..7
  const int dtile = blockIdx.x & 31;
  const int c = blockIdx.y;         // 0..7
  const int d0 = dtile * 32;
  const int da = d0 + 2 * dl, db_ = da + 1;

  const float Av0 = -__expf(A_log[(size_t)da * N_ + n]) * 1.44269504089f;
  const float Av1 = -__expf(A_log[(size_t)db_ * N_ + n]) * 1.44269504089f;

  const int t0 = c * TCH8;
  float cumP0 = 1.f, loc0 = 0.f, S10 = 0.f, S20 = 0.f;
  float cumP1 = 1.f, loc1 = 0.f, S11 = 0.f, S21 = 0.f;
  float xp0 = 0.f, xp1 = 0.f, xp2 = 0.f, xp3 = 0.f;  // xsum partials

  const int srow = tid >> 3, sc4 = (tid & 7) * 4;  // 32 rows x 32 cols
  const int bpos = ((sc4 * 2) & 31) + (sc4 >> 4);  // B/C interleave slot

  // prologue: load tile 0 into registers
  float4 xv_r, dv_r, bc_r;
  {
    const size_t g = ((size_t)b * L_ + t0 + srow) * D_ + d0 + sc4;
    xv_r = *(const float4*)(x + g);
    dv_r = *(const float4*)(dtb + g);
    bc_r = *(const float4*)(xdb + ((size_t)b * L_ + t0 + srow) * 96 + 64 + sc4);
  }

  int cur = 0;
  for (int tile = 0; tile < TCH8 / TB; ++tile) {
    // write the staged registers into buf[cur]
    *(float4*)(&dts[cur][srow][sc4]) = dv_r;
    *(float4*)(&dtx[cur][srow][sc4]) =
        make_float4(xv_r.x * dv_r.x, xv_r.y * dv_r.y, xv_r.z * dv_r.z,
                    xv_r.w * dv_r.w);
    xp0 += xv_r.x; xp1 += xv_r.y; xp2 += xv_r.z; xp3 += xv_r.w;
    bcs[cur][srow][bpos + 0] = bc_r.x;
    bcs[cur][srow][bpos + 2] = bc_r.y;
    bcs[cur][srow][bpos + 4] = bc_r.z;
    bcs[cur][srow][bpos + 6] = bc_r.w;
    __syncthreads();  // the only barrier per tile

    // issue next tile's loads (latency hides under the compute below)
    if (tile + 1 < TCH8 / TB) {
      const int tnext = t0 + (tile + 1) * TB;
      const size_t g = ((size_t)b * L_ + tnext + srow) * D_ + d0 + sc4;
      xv_r = *(const float4*)(x + g);
      dv_r = *(const float4*)(dtb + g);
      bc_r = *(const float4*)(xdb + ((size_t)b * L_ + tnext + srow) * 96 + 64 + sc4);
    }

#pragma unroll
    for (int tt = 0; tt < TB; ++tt) {
      const float2 bv = *(const float2*)(&bcs[cur][tt][2 * n]);  // (B[n],C[n])
      const float2 dv = *(const float2*)(&dts[cur][tt][2 * dl]);
      const float2 px = *(const float2*)(&dtx[cur][tt][2 * dl]);
      const float e0 = exp2_fast(dv.x * Av0);
      cumP0 *= e0;
      loc0 = fmaf(e0, loc0, px.x * bv.x);
      S10 = fmaf(cumP0, bv.y, S10);
      S20 = fmaf(loc0, bv.y, S20);
      const float e1 = exp2_fast(dv.y * Av1);
      cumP1 *= e1;
      loc1 = fmaf(e1, loc1, px.y * bv.x);
      S11 = fmaf(cumP1, bv.y, S11);
      S21 = fmaf(loc1, bv.y, S21);
    }
    cur ^= 1;
  }

  const size_t si0 = (((size_t)c * B_ + b) * D_ + da) * N_ + n;
  const size_t si1 = (((size_t)c * B_ + b) * D_ + db_) * N_ + n;
  ((float4*)summ)[si0] = make_float4(cumP0, S10, S20, loc0);
  ((float4*)summ)[si1] = make_float4(cumP1, S11, S21, loc1);

  // xsum: per-thread partials cover cols sc4..sc4+3. LDS-reduce via dtx[0].
  __syncthreads();
  *(float4*)(&dtx[0][srow][sc4]) = make_float4(xp0, xp1, xp2, xp3);
  __syncthreads();
  if (tid < 32) {
    float s = 0.f;
#pragma unroll
    for (int r = 0; r < 32; ++r) s += dtx[0][r][tid];
    sumx[((size_t)c * B_ + b) * D_ + d0 + tid] = s;
  }
}

// ---------------------------------------------------------------------------
// Kernel 3b: exact sequential chunk combine + n-reduce -> pooled.
// ---------------------------------------------------------------------------
__global__ __launch_bounds__(256) void combine_kernel(
    const float* __restrict__ summ, const float* __restrict__ sumx,
    const float* __restrict__ D_param, float* __restrict__ pooled) {
  const int gid = blockIdx.x * 256 + threadIdx.x;  // 0..131071
  const int n = gid & 15;
  const int d = (gid >> 4) & (D_ - 1);
  const int b = gid >> 14;  // 0..7
  float hin = 0.f, acc = 0.f;
  const float4* s4 = (const float4*)summ;
#pragma unroll
  for (int c = 0; c < CH8; ++c) {
    const float4 f = s4[(((size_t)c * B_ + b) * D_ + d) * N_ + n];
    acc = fmaf(hin, f.y, acc) + f.z;
    hin = fmaf(f.x, hin, f.w);
  }
  acc += __shfl_xor(acc, 1);
  acc += __shfl_xor(acc, 2);
  acc += __shfl_xor(acc, 4);
  acc += __shfl_xor(acc, 8);
  if (n == 0) {
    float xst = 0.f;
#pragma unroll
    for (int c = 0; c < CH8; ++c)
      xst += sumx[((size_t)c * B_ + b) * D_ + d];
    pooled[(size_t)b * D_ + d] =
        (acc + D_param[d] * xst) * (1.0f / (float)L_);
  }
}

// ---------------------------------------------------------------------------
// Kernel 4: logits. One wave per class; all 8 batches from LDS-staged pooled.
// ---------------------------------------------------------------------------
__global__ __launch_bounds__(256) void cls_kernel(
    const float* __restrict__ pooled, const float* __restrict__ W_cls,
    const float* __restrict__ b_cls, float* __restrict__ out) {
  __shared__ float pool[B_ * D_];  // 32 KB
  const int tid = threadIdx.x;
  const int c = blockIdx.x * 4 + (tid >> 6);
  const int lane = tid & 63;

#pragma unroll
  for (int j = 0; j < 8; ++j) {
    const int f4 = tid + j * 256;
    ((float4*)pool)[f4] = ((const float4*)pooled)[f4];
  }
  __syncthreads();

  float accb[B_];
#pragma unroll
  for (int b = 0; b < B_; ++b) accb[b] = 0.f;

#pragma unroll
  for (int i = 0; i < 4; ++i) {
    const float4 wv =
        *(const float4*)(W_cls + (size_t)c * D_ + i * 256 + lane * 4);
#pragma unroll
    for (int b = 0; b < B_; ++b) {
      const float4 p = *(const float4*)(&pool[b * D_ + i * 256 + lane * 4]);
      accb[b] = fmaf(wv.x, p.x,
                fmaf(wv.y, p.y, fmaf(wv.z, p.z, fmaf(wv.w, p.w, accb[b]))));
    }
  }
#pragma unroll
  for (int off = 1; off < 64; off <<= 1) {
#pragma unroll
    for (int b = 0; b < B_; ++b) accb[b] += __shfl_xor(accb[b], off);
  }
  if (lane < B_) out[(size_t)lane * NC_ + c] = accb[lane] + b_cls[c];
}

// ---------------------------------------------------------------------------
extern "C" void kernel_launch(void* const* d_in, const int* in_sizes, int n_in,
                              void* d_out, int out_size, void* d_ws,
                              size_t ws_size, hipStream_t stream) {
  const float* x = (const float*)d_in[0];
  const float* A_log = (const float*)d_in[1];
  const float* D_param = (const float*)d_in[2];
  const float* W_xproj = (const float*)d_in[3];
  const float* W_dt = (const float*)d_in[4];
  const float* b_dt = (const float*)d_in[5];
  const float* W_cls = (const float*)d_in[6];
  const float* b_cls = (const float*)d_in[7];
  float* out = (float*)d_out;

  // ws layout, flat, no aliasing (~79 MB of ~268 MB available):
  float* ws_f = (float*)d_ws;
  float* xdb = ws_f;                               // 786,432 f
  float* part = xdb + (size_t)XP_M * 96;           // 6,291,456 f
  float* dtb = part + (size_t)XP_KS * XP_M * 96;   // 8,388,608 f
  float* summ = dtb + (size_t)XP_M * D_;           // 4,194,304 f
  float* sumx = summ + (size_t)CH8 * B_ * D_ * N_ * 4;  // 65,536 f
  float* pooled = sumx + (size_t)CH8 * B_ * D_;    // 8,192 f

  xproj_kernel<<<dim3(XP_M / XP_TM, XP_KS), dim3(256), 0, stream>>>(
      x, W_xproj, part);
  xreduce_kernel<<<dim3(XP_M * 96 / 4 / 256), dim3(256), 0, stream>>>(part,
                                                                      xdb);
  dt_kernel<<<dim3(XP_M / 64, D_ / 64), dim3(256), 0, stream>>>(xdb, W_dt,
                                                                b_dt, dtb);
  scan_kernel<<<dim3(B_ * 32, CH8), dim3(256), 0, stream>>>(x, xdb, dtb,
                                                            A_log, summ, sumx);
  combine_kernel<<<dim3(B_ * D_ * N_ / 256), dim3(256), 0, stream>>>(
      summ, sumx, D_param, pooled);
  cls_kernel<<<dim3(NC_ / 4), dim3(256), 0, stream>>>(pooled, W_cls, b_cls,
                                                      out);
}